// Round 2
// baseline (71.130 us; speedup 1.0000x reference)
//
#include <hip/hip_runtime.h>

typedef unsigned short u16;
typedef unsigned int u32;
typedef __bf16 bf16x8 __attribute__((ext_vector_type(8)));
typedef float f32x4 __attribute__((ext_vector_type(4)));

#define B_ 8
#define C_ 64
#define H_ 112
#define W_ 112
#define HW_ 12544
#define F_ 128
#define OH_ 110
#define OW_ 110
#define NPOS 96800
#define KK_ 576
#define NWG 757  // ceil(NPOS/128)

__device__ __forceinline__ u16 f2bf(float f) {
  u32 u = __builtin_bit_cast(u32, f);
  u32 r = (u + 0x7fffu + ((u >> 16) & 1u)) >> 16;
  return (u16)r;
}
__device__ __forceinline__ float bf2f(u16 h) {
  u32 u = ((u32)h) << 16;
  return __builtin_bit_cast(float, u);
}

__device__ __forceinline__ void gl_lds16(const void* g, void* l) {
  __builtin_amdgcn_global_load_lds((const __attribute__((address_space(1))) void*)g,
                                   (__attribute__((address_space(3))) void*)l,
                                   16, 0, 0);
}

// ---------------- prep: NCHW fp32 -> NHWC bf16 hi/lo ----------------
__global__ __launch_bounds__(256) void prep_input(const float* __restrict__ in,
                                                  u16* __restrict__ xH,
                                                  u16* __restrict__ xL) {
  __shared__ float tile[C_][W_ + 1];
  const int b = blockIdx.x / H_;
  const int y = blockIdx.x % H_;
  const int tid = threadIdx.x;
  const float* src = in + ((size_t)b * C_ * H_ + y) * W_;
  for (int idx = tid; idx < C_ * W_; idx += 256) {
    int c = idx / W_;
    int x = idx - c * W_;
    tile[c][x] = src[(size_t)c * HW_ + x];
  }
  __syncthreads();
  const size_t obase = ((size_t)(b * H_ + y)) * W_ * C_;
  for (int idx = tid; idx < W_ * (C_ / 2); idx += 256) {
    int x = idx / (C_ / 2);
    int cp = idx - x * (C_ / 2);
    int c = cp * 2;
    float v0 = tile[c][x], v1 = tile[c + 1][x];
    u16 h0 = f2bf(v0), h1 = f2bf(v1);
    u16 l0 = f2bf(v0 - bf2f(h0)), l1 = f2bf(v1 - bf2f(h1));
    u32 hw = (u32)h0 | ((u32)h1 << 16);
    u32 lw = (u32)l0 | ((u32)l1 << 16);
    *(u32*)(xH + obase + (size_t)x * C_ + c) = hw;
    *(u32*)(xL + obase + (size_t)x * C_ + c) = lw;
  }
}

// ---------------- prep: kernel fp32 -> bf16 hi/lo ----------------
__global__ __launch_bounds__(256) void prep_ker(const float* __restrict__ k,
                                                u16* __restrict__ kH,
                                                u16* __restrict__ kL) {
  int idx = blockIdx.x * 256 + threadIdx.x;
  if (idx < F_ * KK_) {
    float v = k[idx];
    u16 h = f2bf(v);
    kH[idx] = h;
    kL[idx] = f2bf(v - bf2f(h));
  }
}

// ---------------- main: implicit GEMM, 2-phase double-buffered ----------------
// 18 K-steps of K=32 (9 taps x 2 halves). LDS: 2 dbuf x {AH,AL,BH,BL} x 8KB = 64KB.
// Per step: stage next (8 gl_lds16/thread), ds_read 16 b128 frags, 48 MFMAs, 1 barrier.
__global__ __launch_bounds__(256, 2) void conv_mfma(
    const u16* __restrict__ xH, const u16* __restrict__ xL,
    const u16* __restrict__ kH, const u16* __restrict__ kL,
    float* __restrict__ out) {
  __shared__ u16 lds[2][4][128 * 32];  // [dbuf][AH,AL,BH,BL][row][k]  row stride 64B

  const int tid = threadIdx.x;
  const int wave = tid >> 6;
  const int lane = tid & 63;

  // bijective XCD-aware block swizzle (m204 form; NWG=757: q=94, r=5)
  const int orig = blockIdx.x;
  const int xcd = orig & 7;
  const int sub = orig >> 3;
  const int wg = (xcd < 5 ? xcd * 95 : 475 + (xcd - 5) * 94) + sub;
  const int n0 = wg * 128;

  // staging geometry: per instr a wave covers 16 rows x 64B; lane -> row=lane>>2, dstoct=lane&3.
  // LDS dest stays linear; SOURCE oct pre-swizzled (m173): q = dstoct ^ (row&3).
  const int rlo = lane >> 2;
  const int q = (lane & 3) ^ (rlo & 3);

  int aOff[2], bOff[2];
#pragma unroll
  for (int it = 0; it < 2; ++it) {
    int row = (it * 4 + wave) * 16 + rlo;
    aOff[it] = row * KK_ + q * 8;
    int n = n0 + row;
    if (n >= NPOS) n = 0;
    int b = n / (OW_ * OH_);
    int r = n - b * (OW_ * OH_);
    int w = r / OH_;
    int h = r - w * OH_;
    bOff[it] = ((b * H_ + h) * W_ + w) * C_ + q * 8;
  }

  const int l15 = lane & 15;
  const int l4 = lane >> 4;
  const int wr = wave >> 1;
  const int wc = wave & 1;

  f32x4 acc[4][4] = {};

  auto stage = [&](int s, int d) {
    const int tap = s >> 1;
    const int half = s & 1;
    const int i = tap / 3;      // W offset
    const int j = tap - i * 3;  // H offset
    const int offA = tap * C_ + half * 32;
    const int offB = (j * W_ + i) * C_ + half * 32;
#pragma unroll
    for (int it = 0; it < 2; ++it) {
      const u32 dst = (u32)((it * 4 + wave) * 1024);
      gl_lds16(kH + aOff[it] + offA, (char*)&lds[d][0][0] + dst);
      gl_lds16(kL + aOff[it] + offA, (char*)&lds[d][1][0] + dst);
      gl_lds16(xH + bOff[it] + offB, (char*)&lds[d][2][0] + dst);
      gl_lds16(xL + bOff[it] + offB, (char*)&lds[d][3][0] + dst);
    }
  };

  stage(0, 0);
  __syncthreads();

  for (int s = 0; s < 18; ++s) {
    const int cur = s & 1;
    if (s < 17) stage(s + 1, cur ^ 1);  // loads fly under this step's compute

    bf16x8 ah[4], al[4], bh[4], bl[4];
#pragma unroll
    for (int mi = 0; mi < 4; ++mi) {
      int row = wr * 64 + mi * 16 + l15;
      int e = row * 32 + ((l4 ^ (row & 3)) * 8);
      ah[mi] = *(const bf16x8*)&lds[cur][0][e];
      al[mi] = *(const bf16x8*)&lds[cur][1][e];
    }
#pragma unroll
    for (int ni = 0; ni < 4; ++ni) {
      int row = wc * 64 + ni * 16 + l15;
      int e = row * 32 + ((l4 ^ (row & 3)) * 8);
      bh[ni] = *(const bf16x8*)&lds[cur][2][e];
      bl[ni] = *(const bf16x8*)&lds[cur][3][e];
    }

#pragma unroll
    for (int mi = 0; mi < 4; ++mi)
#pragma unroll
      for (int ni = 0; ni < 4; ++ni) {
        acc[mi][ni] = __builtin_amdgcn_mfma_f32_16x16x32_bf16(ah[mi], bh[ni], acc[mi][ni], 0, 0, 0);
        acc[mi][ni] = __builtin_amdgcn_mfma_f32_16x16x32_bf16(ah[mi], bl[ni], acc[mi][ni], 0, 0, 0);
        acc[mi][ni] = __builtin_amdgcn_mfma_f32_16x16x32_bf16(al[mi], bh[ni], acc[mi][ni], 0, 0, 0);
      }

    __syncthreads();  // drains vmcnt (next-step loads) + lgkm; one barrier per step
  }

  // epilogue: D col = lane&15 -> n, row = (lane>>4)*4+q -> f
#pragma unroll
  for (int ni = 0; ni < 4; ++ni) {
    int n = n0 + wc * 64 + ni * 16 + l15;
    if (n >= NPOS) continue;
    int b = n / (OW_ * OH_);
    int r = n - b * (OW_ * OH_);
    int w = r / OH_;
    int h = r - w * OH_;
    float* op = out + ((size_t)(b * F_) * OW_ + w) * OH_ + h;
#pragma unroll
    for (int mi = 0; mi < 4; ++mi) {
      int fbase = wr * 64 + mi * 16 + l4 * 4;
#pragma unroll
      for (int qq = 0; qq < 4; ++qq) {
        op[(size_t)(fbase + qq) * (OW_ * OH_)] = acc[mi][ni][qq];
      }
    }
  }
}

// ---------------- correctness fallback (ws too small) ----------------
__global__ void naive_conv(const float* __restrict__ in, const float* __restrict__ ker,
                           float* __restrict__ out) {
  int idx = blockIdx.x * 256 + threadIdx.x;
  const int total = B_ * F_ * OW_ * OH_;
  if (idx >= total) return;
  int h = idx % OH_;
  int w = (idx / OH_) % OW_;
  int f = (idx / (OW_ * OH_)) % F_;
  int b = idx / (F_ * OW_ * OH_);
  float s = 0.f;
  for (int tap = 0; tap < 9; ++tap) {
    int i = tap / 3, j = tap % 3;
    const float* ip = in + ((size_t)b * C_ * H_ + (h + j)) * W_ + (w + i);
    const float* kp = ker + (size_t)f * KK_ + tap * C_;
    for (int c = 0; c < C_; ++c) s += ip[(size_t)c * HW_] * kp[c];
  }
  out[idx] = s;
}

extern "C" void kernel_launch(void* const* d_in, const int* in_sizes, int n_in,
                              void* d_out, int out_size, void* d_ws, size_t ws_size,
                              hipStream_t stream) {
  const float* in = (const float*)d_in[0];
  const float* ker = (const float*)d_in[1];
  float* out = (float*)d_out;

  const size_t xElems = (size_t)B_ * H_ * W_ * C_;  // 6,422,528
  const size_t kElems = (size_t)F_ * KK_;           // 73,728
  const size_t need = xElems * 2 * 2 + kElems * 2 * 2;

  if (ws_size < need) {
    int total = B_ * F_ * OW_ * OH_;
    naive_conv<<<(total + 255) / 256, 256, 0, stream>>>(in, ker, out);
    return;
  }

  u16* xH = (u16*)d_ws;
  u16* xL = xH + xElems;
  u16* kH = xL + xElems;
  u16* kL = kH + kElems;

  prep_input<<<B_ * H_, 256, 0, stream>>>(in, xH, xL);
  prep_ker<<<(int)((kElems + 255) / 256), 256, 0, stream>>>(ker, kH, kL);
  conv_mfma<<<NWG, 256, 0, stream>>>(xH, xL, kH, kL, out);
}

// Round 3
// 70.756 us; speedup vs baseline: 1.0053x; 1.0053x over previous
//
#include <hip/hip_runtime.h>

typedef unsigned short u16;
typedef unsigned int u32;
typedef __bf16 bf16x8 __attribute__((ext_vector_type(8)));
typedef float f32x4 __attribute__((ext_vector_type(4)));

#define B_ 8
#define C_ 64
#define H_ 112
#define W_ 112
#define HW_ 12544
#define F_ 128
#define OH_ 110
#define OW_ 110
#define NPOS 96800
#define KK_ 576
#define NWG 757  // ceil(NPOS/128)

__device__ __forceinline__ u16 f2bf(float f) {
  u32 u = __builtin_bit_cast(u32, f);
  u32 r = (u + 0x7fffu + ((u >> 16) & 1u)) >> 16;
  return (u16)r;
}
__device__ __forceinline__ float bf2f(u16 h) {
  u32 u = ((u32)h) << 16;
  return __builtin_bit_cast(float, u);
}

__device__ __forceinline__ void gl_lds16(const void* g, void* l) {
  __builtin_amdgcn_global_load_lds((const __attribute__((address_space(1))) void*)g,
                                   (__attribute__((address_space(3))) void*)l,
                                   16, 0, 0);
}

// ---------------- prep: NCHW fp32 -> NHWC bf16 hi/lo ----------------
__global__ __launch_bounds__(256) void prep_input(const float* __restrict__ in,
                                                  u16* __restrict__ xH,
                                                  u16* __restrict__ xL) {
  __shared__ float tile[C_][W_ + 1];
  const int b = blockIdx.x / H_;
  const int y = blockIdx.x % H_;
  const int tid = threadIdx.x;
  const float* src = in + ((size_t)b * C_ * H_ + y) * W_;
  for (int idx = tid; idx < C_ * W_; idx += 256) {
    int c = idx / W_;
    int x = idx - c * W_;
    tile[c][x] = src[(size_t)c * HW_ + x];
  }
  __syncthreads();
  const size_t obase = ((size_t)(b * H_ + y)) * W_ * C_;
  for (int idx = tid; idx < W_ * (C_ / 2); idx += 256) {
    int x = idx / (C_ / 2);
    int cp = idx - x * (C_ / 2);
    int c = cp * 2;
    float v0 = tile[c][x], v1 = tile[c + 1][x];
    u16 h0 = f2bf(v0), h1 = f2bf(v1);
    u16 l0 = f2bf(v0 - bf2f(h0)), l1 = f2bf(v1 - bf2f(h1));
    u32 hw = (u32)h0 | ((u32)h1 << 16);
    u32 lw = (u32)l0 | ((u32)l1 << 16);
    *(u32*)(xH + obase + (size_t)x * C_ + c) = hw;
    *(u32*)(xL + obase + (size_t)x * C_ + c) = lw;
  }
}

// ---------------- prep: kernel fp32 -> bf16 hi/lo ----------------
__global__ __launch_bounds__(256) void prep_ker(const float* __restrict__ k,
                                                u16* __restrict__ kH,
                                                u16* __restrict__ kL) {
  int idx = blockIdx.x * 256 + threadIdx.x;
  if (idx < F_ * KK_) {
    float v = k[idx];
    u16 h = f2bf(v);
    kH[idx] = h;
    kL[idx] = f2bf(v - bf2f(h));
  }
}

// ---------------- main: implicit GEMM, 2-phase double-buffered ----------------
// 18 K-steps of K=32 (9 taps x 2 halves). LDS: 2 dbuf x {AH,AL,BH,BL} x 8KB = 64KB.
// Rows are 64B (16 banks): bank-quad og = (row&1)*4 + oct, so the conflict-free
// involution is oct ^= (row>>1)&3 (og walks all 8 quads over 8 rows; 2-way over 16
// rows = free per m136). Round-1's oct^=(row&3) was a 4-way conflict (3.5M counter).
__global__ __launch_bounds__(256, 2) void conv_mfma(
    const u16* __restrict__ xH, const u16* __restrict__ xL,
    const u16* __restrict__ kH, const u16* __restrict__ kL,
    float* __restrict__ out) {
  __shared__ u16 lds[2][4][128 * 32];  // [dbuf][AH,AL,BH,BL][row][k]  row stride 64B

  const int tid = threadIdx.x;
  const int wave = tid >> 6;
  const int lane = tid & 63;

  // bijective XCD-aware block swizzle (m204 form; NWG=757: q=94, r=5)
  const int orig = blockIdx.x;
  const int xcd = orig & 7;
  const int sub = orig >> 3;
  const int wg = (xcd < 5 ? xcd * 95 : 475 + (xcd - 5) * 94) + sub;
  const int n0 = wg * 128;

  // staging geometry: per instr a wave covers 16 rows x 64B; lane -> row=lane>>2,
  // dstoct=lane&3. LDS dest linear; SOURCE oct pre-swizzled with the SAME involution:
  // q = dstoct ^ ((row>>1)&3) = (lane&3) ^ ((lane>>3)&3).
  const int rlo = lane >> 2;
  const int q = (lane & 3) ^ ((lane >> 3) & 3);

  int aOff[2], bOff[2];
#pragma unroll
  for (int it = 0; it < 2; ++it) {
    int row = (it * 4 + wave) * 16 + rlo;
    aOff[it] = row * KK_ + q * 8;
    int n = n0 + row;
    if (n >= NPOS) n = 0;
    int b = n / (OW_ * OH_);
    int r = n - b * (OW_ * OH_);
    int w = r / OH_;
    int h = r - w * OH_;
    bOff[it] = ((b * H_ + h) * W_ + w) * C_ + q * 8;
  }

  const int l15 = lane & 15;
  const int l4 = lane >> 4;
  const int wr = wave >> 1;
  const int wc = wave & 1;

  f32x4 acc[4][4] = {};

  auto stage = [&](int s, int d) {
    const int tap = s >> 1;
    const int half = s & 1;
    const int i = tap / 3;      // W offset
    const int j = tap - i * 3;  // H offset
    const int offA = tap * C_ + half * 32;
    const int offB = (j * W_ + i) * C_ + half * 32;
#pragma unroll
    for (int it = 0; it < 2; ++it) {
      const u32 dst = (u32)((it * 4 + wave) * 1024);
      gl_lds16(kH + aOff[it] + offA, (char*)&lds[d][0][0] + dst);
      gl_lds16(kL + aOff[it] + offA, (char*)&lds[d][1][0] + dst);
      gl_lds16(xH + bOff[it] + offB, (char*)&lds[d][2][0] + dst);
      gl_lds16(xL + bOff[it] + offB, (char*)&lds[d][3][0] + dst);
    }
  };

  stage(0, 0);
  __syncthreads();

  for (int s = 0; s < 18; ++s) {
    const int cur = s & 1;
    if (s < 17) stage(s + 1, cur ^ 1);  // loads fly under this step's compute

    bf16x8 ah[4], al[4], bh[4], bl[4];
#pragma unroll
    for (int mi = 0; mi < 4; ++mi) {
      int row = wr * 64 + mi * 16 + l15;
      int e = row * 32 + ((l4 ^ ((row >> 1) & 3)) * 8);
      ah[mi] = *(const bf16x8*)&lds[cur][0][e];
      al[mi] = *(const bf16x8*)&lds[cur][1][e];
    }
#pragma unroll
    for (int ni = 0; ni < 4; ++ni) {
      int row = wc * 64 + ni * 16 + l15;
      int e = row * 32 + ((l4 ^ ((row >> 1) & 3)) * 8);
      bh[ni] = *(const bf16x8*)&lds[cur][2][e];
      bl[ni] = *(const bf16x8*)&lds[cur][3][e];
    }

#pragma unroll
    for (int mi = 0; mi < 4; ++mi)
#pragma unroll
      for (int ni = 0; ni < 4; ++ni) {
        acc[mi][ni] = __builtin_amdgcn_mfma_f32_16x16x32_bf16(ah[mi], bh[ni], acc[mi][ni], 0, 0, 0);
        acc[mi][ni] = __builtin_amdgcn_mfma_f32_16x16x32_bf16(ah[mi], bl[ni], acc[mi][ni], 0, 0, 0);
        acc[mi][ni] = __builtin_amdgcn_mfma_f32_16x16x32_bf16(al[mi], bh[ni], acc[mi][ni], 0, 0, 0);
      }

    __syncthreads();  // drains vmcnt (next-step loads) + lgkm; one barrier per step
  }

  // epilogue: D col = lane&15 -> n, row = (lane>>4)*4+q -> f
#pragma unroll
  for (int ni = 0; ni < 4; ++ni) {
    int n = n0 + wc * 64 + ni * 16 + l15;
    if (n >= NPOS) continue;
    int b = n / (OW_ * OH_);
    int r = n - b * (OW_ * OH_);
    int w = r / OH_;
    int h = r - w * OH_;
    float* op = out + ((size_t)(b * F_) * OW_ + w) * OH_ + h;
#pragma unroll
    for (int mi = 0; mi < 4; ++mi) {
      int fbase = wr * 64 + mi * 16 + l4 * 4;
#pragma unroll
      for (int qq = 0; qq < 4; ++qq) {
        op[(size_t)(fbase + qq) * (OW_ * OH_)] = acc[mi][ni][qq];
      }
    }
  }
}

// ---------------- correctness fallback (ws too small) ----------------
__global__ void naive_conv(const float* __restrict__ in, const float* __restrict__ ker,
                           float* __restrict__ out) {
  int idx = blockIdx.x * 256 + threadIdx.x;
  const int total = B_ * F_ * OW_ * OH_;
  if (idx >= total) return;
  int h = idx % OH_;
  int w = (idx / OH_) % OW_;
  int f = (idx / (OW_ * OH_)) % F_;
  int b = idx / (F_ * OW_ * OH_);
  float s = 0.f;
  for (int tap = 0; tap < 9; ++tap) {
    int i = tap / 3, j = tap % 3;
    const float* ip = in + ((size_t)b * C_ * H_ + (h + j)) * W_ + (w + i);
    const float* kp = ker + (size_t)f * KK_ + tap * C_;
    for (int c = 0; c < C_; ++c) s += ip[(size_t)c * HW_] * kp[c];
  }
  out[idx] = s;
}

extern "C" void kernel_launch(void* const* d_in, const int* in_sizes, int n_in,
                              void* d_out, int out_size, void* d_ws, size_t ws_size,
                              hipStream_t stream) {
  const float* in = (const float*)d_in[0];
  const float* ker = (const float*)d_in[1];
  float* out = (float*)d_out;

  const size_t xElems = (size_t)B_ * H_ * W_ * C_;  // 6,422,528
  const size_t kElems = (size_t)F_ * KK_;           // 73,728
  const size_t need = xElems * 2 * 2 + kElems * 2 * 2;

  if (ws_size < need) {
    int total = B_ * F_ * OW_ * OH_;
    naive_conv<<<(total + 255) / 256, 256, 0, stream>>>(in, ker, out);
    return;
  }

  u16* xH = (u16*)d_ws;
  u16* xL = xH + xElems;
  u16* kH = xL + xElems;
  u16* kL = kH + kElems;

  prep_input<<<B_ * H_, 256, 0, stream>>>(in, xH, xL);
  prep_ker<<<(int)((kElems + 255) / 256), 256, 0, stream>>>(ker, kH, kL);
  conv_mfma<<<NWG, 256, 0, stream>>>(xH, xL, kH, kL, out);
}

// Round 4
// 64.204 us; speedup vs baseline: 1.1079x; 1.1021x over previous
//
#include <hip/hip_runtime.h>

typedef unsigned short u16;
typedef unsigned int u32;
typedef __bf16 bf16x8 __attribute__((ext_vector_type(8)));
typedef float f32x4 __attribute__((ext_vector_type(4)));

#define B_ 8
#define C_ 64
#define H_ 112
#define W_ 112
#define HW_ 12544
#define F_ 128
#define OH_ 110
#define OW_ 110
#define NPOS 96800
#define KK_ 576
#define NWG 757  // ceil(NPOS/128)

__device__ __forceinline__ u16 f2bf(float f) {
  u32 u = __builtin_bit_cast(u32, f);
  u32 r = (u + 0x7fffu + ((u >> 16) & 1u)) >> 16;
  return (u16)r;
}
__device__ __forceinline__ float bf2f(u16 h) {
  u32 u = ((u32)h) << 16;
  return __builtin_bit_cast(float, u);
}

__device__ __forceinline__ void gl_lds16(const void* g, void* l) {
  __builtin_amdgcn_global_load_lds((const __attribute__((address_space(1))) void*)g,
                                   (__attribute__((address_space(3))) void*)l,
                                   16, 0, 0);
}

// ---------------- prep: NCHW fp32 -> NHWC bf16 hi/lo ----------------
__global__ __launch_bounds__(256) void prep_input(const float* __restrict__ in,
                                                  u16* __restrict__ xH,
                                                  u16* __restrict__ xL) {
  __shared__ float tile[C_][W_ + 1];
  const int b = blockIdx.x / H_;
  const int y = blockIdx.x % H_;
  const int tid = threadIdx.x;
  const float* src = in + ((size_t)b * C_ * H_ + y) * W_;
  for (int idx = tid; idx < C_ * W_; idx += 256) {
    int c = idx / W_;
    int x = idx - c * W_;
    tile[c][x] = src[(size_t)c * HW_ + x];
  }
  __syncthreads();
  const size_t obase = ((size_t)(b * H_ + y)) * W_ * C_;
  for (int idx = tid; idx < W_ * (C_ / 2); idx += 256) {
    int x = idx / (C_ / 2);
    int cp = idx - x * (C_ / 2);
    int c = cp * 2;
    float v0 = tile[c][x], v1 = tile[c + 1][x];
    u16 h0 = f2bf(v0), h1 = f2bf(v1);
    u16 l0 = f2bf(v0 - bf2f(h0)), l1 = f2bf(v1 - bf2f(h1));
    u32 hw = (u32)h0 | ((u32)h1 << 16);
    u32 lw = (u32)l0 | ((u32)l1 << 16);
    *(u32*)(xH + obase + (size_t)x * C_ + c) = hw;
    *(u32*)(xL + obase + (size_t)x * C_ + c) = lw;
  }
}

// ---------------- prep: kernel fp32 -> bf16 hi/lo ----------------
__global__ __launch_bounds__(256) void prep_ker(const float* __restrict__ k,
                                                u16* __restrict__ kH,
                                                u16* __restrict__ kL) {
  int idx = blockIdx.x * 256 + threadIdx.x;
  if (idx < F_ * KK_) {
    float v = k[idx];
    u16 h = f2bf(v);
    kH[idx] = h;
    kL[idx] = f2bf(v - bf2f(h));
  }
}

// ---------------- main: implicit GEMM, single-buffer K=32, occupancy-first ----
// 18 K-steps of K=32. LDS: {AH,AL,BH,BL} x 8KB = 32KB -> 4 blocks/CU (16 waves).
// Grid 757 <= 4*256: ALL blocks co-resident, no tail. TLP (m114) hides the serial
// stage phase across the 4 resident blocks (m97 mechanism).
// Rows 64B (16 banks): conflict-free involution oct ^= (row>>1)&3 (verified r3: 0).
__global__ __launch_bounds__(256, 4) void conv_mfma(
    const u16* __restrict__ xH, const u16* __restrict__ xL,
    const u16* __restrict__ kH, const u16* __restrict__ kL,
    float* __restrict__ out) {
  __shared__ u16 lds[4][128 * 32];  // [AH,AL,BH,BL][row][k]  row stride 64B

  const int tid = threadIdx.x;
  const int wave = tid >> 6;
  const int lane = tid & 63;

  // bijective XCD-aware block swizzle (m204 form; NWG=757: q=94, r=5)
  const int orig = blockIdx.x;
  const int xcd = orig & 7;
  const int sub = orig >> 3;
  const int wg = (xcd < 5 ? xcd * 95 : 475 + (xcd - 5) * 94) + sub;
  const int n0 = wg * 128;

  // staging: per instr a wave covers 16 rows x 64B; lane -> row=lane>>2, dstoct=lane&3.
  // LDS dest linear; SOURCE oct pre-swizzled with the read involution:
  // q = dstoct ^ ((row>>1)&3) = (lane&3) ^ ((lane>>3)&3).
  const int rlo = lane >> 2;
  const int q = (lane & 3) ^ ((lane >> 3) & 3);

  int aOff[2], bOff[2];
#pragma unroll
  for (int it = 0; it < 2; ++it) {
    int row = (it * 4 + wave) * 16 + rlo;
    aOff[it] = row * KK_ + q * 8;
    int n = n0 + row;
    if (n >= NPOS) n = 0;
    int b = n / (OW_ * OH_);
    int r = n - b * (OW_ * OH_);
    int w = r / OH_;
    int h = r - w * OH_;
    bOff[it] = ((b * H_ + h) * W_ + w) * C_ + q * 8;
  }

  const int l15 = lane & 15;
  const int l4 = lane >> 4;
  const int wr = wave >> 1;
  const int wc = wave & 1;

  f32x4 acc[4][4] = {};

  for (int s = 0; s < 18; ++s) {
    const int tap = s >> 1;
    const int half = s & 1;
    const int i = tap / 3;      // W offset
    const int j = tap - i * 3;  // H offset
    const int offA = tap * C_ + half * 32;
    const int offB = (j * W_ + i) * C_ + half * 32;

    __syncthreads();  // WAR: previous step's reads done before overwrite
#pragma unroll
    for (int it = 0; it < 2; ++it) {
      const u32 dst = (u32)((it * 4 + wave) * 1024);
      gl_lds16(kH + aOff[it] + offA, (char*)&lds[0][0] + dst);
      gl_lds16(kL + aOff[it] + offA, (char*)&lds[1][0] + dst);
      gl_lds16(xH + bOff[it] + offB, (char*)&lds[2][0] + dst);
      gl_lds16(xL + bOff[it] + offB, (char*)&lds[3][0] + dst);
    }
    __syncthreads();  // staged data visible (compiler drains vmcnt)

    bf16x8 ah[4], al[4], bh[4], bl[4];
#pragma unroll
    for (int mi = 0; mi < 4; ++mi) {
      int row = wr * 64 + mi * 16 + l15;
      int e = row * 32 + ((l4 ^ ((row >> 1) & 3)) * 8);
      ah[mi] = *(const bf16x8*)&lds[0][e];
      al[mi] = *(const bf16x8*)&lds[1][e];
    }
#pragma unroll
    for (int ni = 0; ni < 4; ++ni) {
      int row = wc * 64 + ni * 16 + l15;
      int e = row * 32 + ((l4 ^ ((row >> 1) & 3)) * 8);
      bh[ni] = *(const bf16x8*)&lds[2][e];
      bl[ni] = *(const bf16x8*)&lds[3][e];
    }

#pragma unroll
    for (int mi = 0; mi < 4; ++mi)
#pragma unroll
      for (int ni = 0; ni < 4; ++ni) {
        acc[mi][ni] = __builtin_amdgcn_mfma_f32_16x16x32_bf16(ah[mi], bh[ni], acc[mi][ni], 0, 0, 0);
        acc[mi][ni] = __builtin_amdgcn_mfma_f32_16x16x32_bf16(ah[mi], bl[ni], acc[mi][ni], 0, 0, 0);
        acc[mi][ni] = __builtin_amdgcn_mfma_f32_16x16x32_bf16(al[mi], bh[ni], acc[mi][ni], 0, 0, 0);
      }
  }

  // epilogue: D col = lane&15 -> n, row = (lane>>4)*4+q -> f
#pragma unroll
  for (int ni = 0; ni < 4; ++ni) {
    int n = n0 + wc * 64 + ni * 16 + l15;
    if (n >= NPOS) continue;
    int b = n / (OW_ * OH_);
    int r = n - b * (OW_ * OH_);
    int w = r / OH_;
    int h = r - w * OH_;
    float* op = out + ((size_t)(b * F_) * OW_ + w) * OH_ + h;
#pragma unroll
    for (int mi = 0; mi < 4; ++mi) {
      int fbase = wr * 64 + mi * 16 + l4 * 4;
#pragma unroll
      for (int qq = 0; qq < 4; ++qq) {
        op[(size_t)(fbase + qq) * (OW_ * OH_)] = acc[mi][ni][qq];
      }
    }
  }
}

// ---------------- correctness fallback (ws too small) ----------------
__global__ void naive_conv(const float* __restrict__ in, const float* __restrict__ ker,
                           float* __restrict__ out) {
  int idx = blockIdx.x * 256 + threadIdx.x;
  const int total = B_ * F_ * OW_ * OH_;
  if (idx >= total) return;
  int h = idx % OH_;
  int w = (idx / OH_) % OW_;
  int f = (idx / (OW_ * OH_)) % F_;
  int b = idx / (F_ * OW_ * OH_);
  float s = 0.f;
  for (int tap = 0; tap < 9; ++tap) {
    int i = tap / 3, j = tap % 3;
    const float* ip = in + ((size_t)b * C_ * H_ + (h + j)) * W_ + (w + i);
    const float* kp = ker + (size_t)f * KK_ + tap * C_;
    for (int c = 0; c < C_; ++c) s += ip[(size_t)c * HW_] * kp[c];
  }
  out[idx] = s;
}

extern "C" void kernel_launch(void* const* d_in, const int* in_sizes, int n_in,
                              void* d_out, int out_size, void* d_ws, size_t ws_size,
                              hipStream_t stream) {
  const float* in = (const float*)d_in[0];
  const float* ker = (const float*)d_in[1];
  float* out = (float*)d_out;

  const size_t xElems = (size_t)B_ * H_ * W_ * C_;  // 6,422,528
  const size_t kElems = (size_t)F_ * KK_;           // 73,728
  const size_t need = xElems * 2 * 2 + kElems * 2 * 2;

  if (ws_size < need) {
    int total = B_ * F_ * OW_ * OH_;
    naive_conv<<<(total + 255) / 256, 256, 0, stream>>>(in, ker, out);
    return;
  }

  u16* xH = (u16*)d_ws;
  u16* xL = xH + xElems;
  u16* kH = xL + xElems;
  u16* kL = kH + kElems;

  prep_input<<<B_ * H_, 256, 0, stream>>>(in, xH, xL);
  prep_ker<<<(int)((kElems + 255) / 256), 256, 0, stream>>>(ker, kH, kL);
  conv_mfma<<<NWG, 256, 0, stream>>>(xH, xL, kH, kL, out);
}

// Round 5
// 63.619 us; speedup vs baseline: 1.1181x; 1.0092x over previous
//
#include <hip/hip_runtime.h>

typedef unsigned short u16;
typedef unsigned int u32;
typedef __bf16 bf16x8 __attribute__((ext_vector_type(8)));
typedef float f32x4 __attribute__((ext_vector_type(4)));

#define B_ 8
#define C_ 64
#define H_ 112
#define W_ 112
#define HW_ 12544
#define F_ 128
#define OH_ 110
#define OW_ 110
#define NPOS 96800
#define KK_ 576
#define NWG 757        // ceil(NPOS/128)
#define OCTSTRIDE 802816  // B_*W_*H_*8 u16 elems per c-oct plane

__device__ __forceinline__ u16 f2bf(float f) {
  u32 u = __builtin_bit_cast(u32, f);
  u32 r = (u + 0x7fffu + ((u >> 16) & 1u)) >> 16;
  return (u16)r;
}
__device__ __forceinline__ float bf2f(u16 h) {
  u32 u = ((u32)h) << 16;
  return __builtin_bit_cast(float, u);
}

__device__ __forceinline__ void gl_lds16(const void* g, void* l) {
  __builtin_amdgcn_global_load_lds((const __attribute__((address_space(1))) void*)g,
                                   (__attribute__((address_space(3))) void*)l,
                                   16, 0, 0);
}

// ---- prep: NCHW fp32 -> [c_oct][b][w][h]{8c} bf16 hi/lo (B-operand direct-load layout) ----
// Quarter-wave B-loads in conv read 16 lanes x 16B at consecutive h -> 256B contiguous.
__global__ __launch_bounds__(256) void prep_inputT(const float* __restrict__ in,
                                                   u16* __restrict__ xTH,
                                                   u16* __restrict__ xTL) {
  __shared__ float tile[8][8][113];  // [c][h][w], w-pad 1 (lane stride 113%32=17: conflict-free)
  const int bid = blockIdx.x;        // 8 b x 8 oct x 14 h-stripes = 896
  const int b = bid / 112;
  const int r = bid % 112;
  const int oct = r / 14;
  const int hs = (r % 14) * 8;
  const int tid = threadIdx.x;

  for (int idx = tid; idx < 8 * 8 * 112; idx += 256) {
    int c = idx / 896;
    int rem = idx - c * 896;
    int h = rem / 112;
    int w = rem - h * 112;
    tile[c][h][w] = in[(((size_t)(b * 64 + oct * 8 + c)) * 112 + (hs + h)) * 112 + w];
  }
  __syncthreads();

  for (int idx = tid; idx < 896; idx += 256) {
    int w = idx >> 3;
    int h = idx & 7;
    u32 hw[4], lw[4];
#pragma unroll
    for (int c2 = 0; c2 < 4; ++c2) {
      float v0 = tile[c2 * 2][h][w], v1 = tile[c2 * 2 + 1][h][w];
      u16 h0 = f2bf(v0), h1 = f2bf(v1);
      u16 l0 = f2bf(v0 - bf2f(h0)), l1 = f2bf(v1 - bf2f(h1));
      hw[c2] = (u32)h0 | ((u32)h1 << 16);
      lw[c2] = (u32)l0 | ((u32)l1 << 16);
    }
    size_t o = ((((size_t)oct * B_ + b) * W_ + w) * H_ + (hs + h)) * 8;
    uint4 hv = {hw[0], hw[1], hw[2], hw[3]};
    uint4 lv = {lw[0], lw[1], lw[2], lw[3]};
    *(uint4*)(xTH + o) = hv;
    *(uint4*)(xTL + o) = lv;
  }
}

// ---------------- prep: kernel fp32 -> bf16 hi/lo ----------------
__global__ __launch_bounds__(256) void prep_ker(const float* __restrict__ k,
                                                u16* __restrict__ kH,
                                                u16* __restrict__ kL) {
  int idx = blockIdx.x * 256 + threadIdx.x;
  if (idx < F_ * KK_) {
    float v = k[idx];
    u16 h = f2bf(v);
    kH[idx] = h;
    kL[idx] = f2bf(v - bf2f(h));
  }
}

// ---------------- main: A-only LDS (2x16KB dbuf), B direct from L2 to regs ----------------
// LDS traffic halves vs r4 (1.32GB -> 0.65GB): A staged 16KB/step, read 32KB/step/block.
// B frag = per-lane 16B dwordx4 from [oct][b][w][h] layout; quarter-wave = 256B contiguous.
// A rows 64B: conflict-free involution oct ^= (row>>1)&3 (verified 0 conflicts r3/r4).
__global__ __launch_bounds__(256, 3) void conv_mfma(
    const u16* __restrict__ xTH, const u16* __restrict__ xTL,
    const u16* __restrict__ kH, const u16* __restrict__ kL,
    float* __restrict__ out) {
  __shared__ u16 lds[2][2][128 * 32];  // [dbuf][H,L][row][k]  row stride 64B

  const int tid = threadIdx.x;
  const int wave = tid >> 6;
  const int lane = tid & 63;

  // bijective XCD-aware block swizzle (m204 form; NWG=757: q=94, r=5)
  const int orig = blockIdx.x;
  const int xcd = orig & 7;
  const int sub = orig >> 3;
  const int wg = (xcd < 5 ? xcd * 95 : 475 + (xcd - 5) * 94) + sub;
  const int n0 = wg * 128;

  const int l15 = lane & 15;
  const int l4 = lane >> 4;
  const int wr = wave >> 1;
  const int wc = wave & 1;

  // ---- A staging geometry (per instr: 16 rows x 64B, LDS dest linear, source pre-swizzled)
  const int rlo = lane >> 2;
  const int q = (lane & 3) ^ ((lane >> 3) & 3);
  int aOff[2];
#pragma unroll
  for (int it = 0; it < 2; ++it) {
    int row = (it * 4 + wave) * 16 + rlo;
    aOff[it] = row * KK_ + q * 8;
  }

  // ---- B addressing: per-lane position offsets (u16 elems), one per ni
  int posOff[4];
#pragma unroll
  for (int ni = 0; ni < 4; ++ni) {
    int n = n0 + wc * 64 + ni * 16 + l15;
    if (n >= NPOS) n = 0;
    int b = n / (OW_ * OH_);
    int r = n - b * (OW_ * OH_);
    int w = r / OH_;
    int h = r - w * OH_;
    posOff[ni] = ((b * W_ + w) * H_ + h) * 8;
  }
  const int l4Off = l4 * OCTSTRIDE;

  f32x4 acc[4][4] = {};

  auto stageA = [&](int s, int d) {
    const int tap = s >> 1;
    const int half = s & 1;
    const int offA = tap * C_ + half * 32;
#pragma unroll
    for (int it = 0; it < 2; ++it) {
      const u32 dst = (u32)((it * 4 + wave) * 1024);
      gl_lds16(kH + aOff[it] + offA, (char*)&lds[d][0][0] + dst);
      gl_lds16(kL + aOff[it] + offA, (char*)&lds[d][1][0] + dst);
    }
  };

  stageA(0, 0);
  __syncthreads();

  for (int s = 0; s < 18; ++s) {
    const int cur = s & 1;
    if (s < 17) stageA(s + 1, cur ^ 1);  // A prefetch flies under this step

    const int tap = s >> 1;
    const int half = s & 1;
    const int i = tap / 3;      // W offset
    const int j = tap - i * 3;  // H offset
    const int sShift = (i * H_ + j) * 8 + half * 4 * OCTSTRIDE;

    // B: 8 per-lane dwordx4 from L2 (no LDS)
    bf16x8 bh[4], bl[4];
#pragma unroll
    for (int ni = 0; ni < 4; ++ni) {
      const int e = posOff[ni] + l4Off + sShift;
      bh[ni] = *(const bf16x8*)(xTH + e);
      bl[ni] = *(const bf16x8*)(xTL + e);
    }

    // A: 8 ds_read_b128 from current buffer
    bf16x8 ah[4], al[4];
#pragma unroll
    for (int mi = 0; mi < 4; ++mi) {
      int row = wr * 64 + mi * 16 + l15;
      int e = row * 32 + ((l4 ^ ((row >> 1) & 3)) * 8);
      ah[mi] = *(const bf16x8*)&lds[cur][0][e];
      al[mi] = *(const bf16x8*)&lds[cur][1][e];
    }

#pragma unroll
    for (int mi = 0; mi < 4; ++mi)
#pragma unroll
      for (int ni = 0; ni < 4; ++ni) {
        acc[mi][ni] = __builtin_amdgcn_mfma_f32_16x16x32_bf16(ah[mi], bh[ni], acc[mi][ni], 0, 0, 0);
        acc[mi][ni] = __builtin_amdgcn_mfma_f32_16x16x32_bf16(ah[mi], bl[ni], acc[mi][ni], 0, 0, 0);
        acc[mi][ni] = __builtin_amdgcn_mfma_f32_16x16x32_bf16(al[mi], bh[ni], acc[mi][ni], 0, 0, 0);
      }

    __syncthreads();  // next A buffer staged-visible; WAR for the buffer we just read
  }

  // epilogue: D col = lane&15 -> n, row = (lane>>4)*4+q -> f
#pragma unroll
  for (int ni = 0; ni < 4; ++ni) {
    int n = n0 + wc * 64 + ni * 16 + l15;
    if (n >= NPOS) continue;
    int b = n / (OW_ * OH_);
    int r = n - b * (OW_ * OH_);
    int w = r / OH_;
    int h = r - w * OH_;
    float* op = out + ((size_t)(b * F_) * OW_ + w) * OH_ + h;
#pragma unroll
    for (int mi = 0; mi < 4; ++mi) {
      int fbase = wr * 64 + mi * 16 + l4 * 4;
#pragma unroll
      for (int qq = 0; qq < 4; ++qq) {
        op[(size_t)(fbase + qq) * (OW_ * OH_)] = acc[mi][ni][qq];
      }
    }
  }
}

// ---------------- correctness fallback (ws too small) ----------------
__global__ void naive_conv(const float* __restrict__ in, const float* __restrict__ ker,
                           float* __restrict__ out) {
  int idx = blockIdx.x * 256 + threadIdx.x;
  const int total = B_ * F_ * OW_ * OH_;
  if (idx >= total) return;
  int h = idx % OH_;
  int w = (idx / OH_) % OW_;
  int f = (idx / (OW_ * OH_)) % F_;
  int b = idx / (F_ * OW_ * OH_);
  float s = 0.f;
  for (int tap = 0; tap < 9; ++tap) {
    int i = tap / 3, j = tap % 3;
    const float* ip = in + ((size_t)b * C_ * H_ + (h + j)) * W_ + (w + i);
    const float* kp = ker + (size_t)f * KK_ + tap * C_;
    for (int c = 0; c < C_; ++c) s += ip[(size_t)c * HW_] * kp[c];
  }
  out[idx] = s;
}

extern "C" void kernel_launch(void* const* d_in, const int* in_sizes, int n_in,
                              void* d_out, int out_size, void* d_ws, size_t ws_size,
                              hipStream_t stream) {
  const float* in = (const float*)d_in[0];
  const float* ker = (const float*)d_in[1];
  float* out = (float*)d_out;

  const size_t xElems = (size_t)B_ * H_ * W_ * C_;  // 6,422,528
  const size_t kElems = (size_t)F_ * KK_;           // 73,728
  const size_t need = xElems * 2 * 2 + kElems * 2 * 2;

  if (ws_size < need) {
    int total = B_ * F_ * OW_ * OH_;
    naive_conv<<<(total + 255) / 256, 256, 0, stream>>>(in, ker, out);
    return;
  }

  u16* xTH = (u16*)d_ws;
  u16* xTL = xTH + xElems;
  u16* kH = xTL + xElems;
  u16* kL = kH + kElems;

  prep_inputT<<<896, 256, 0, stream>>>(in, xTH, xTL);
  prep_ker<<<(int)((kElems + 255) / 256), 256, 0, stream>>>(ker, kH, kL);
  conv_mfma<<<NWG, 256, 0, stream>>>(xTH, xTL, kH, kL, out);
}